// Round 10
// baseline (244.550 us; speedup 1.0000x reference)
//
#include <hip/hip_runtime.h>
#include <cstdint>

#define C_ 128
#define L_ 16
#define G_ 4
#define H_ 56
#define W_ 56
#define HW_ 3136
#define CH_ 4                     // channels per chunk
#define NCK_ 8                    // chunks
#define RS_ 64                    // xs row stride (floats), 16 x 16B blocks
#define XS_F (CH_ * 14 * RS_)     // 3584 floats per chunk buffer
#define LDS_F (2 * XS_F)          // 7168 floats (dbuf)
#define PAD_F 6656                // pad -> 55296 B total -> 2 blocks/CU

typedef float f4 __attribute__((ext_vector_type(4)));
typedef __attribute__((address_space(3))) uint32_t lds_u32;
typedef const __attribute__((address_space(1))) uint32_t glb_u32;

// Block = (b, t, g, htile of 8 rows), 448 thr = 7 waves; wave w owns dy=w
// (wave-uniform -> weights via s_load, xs LDS reads perfectly bank-uniform).
// Lane = 8 tx (w-seg of 8; tx==7 dup/store-masked) x 8 h. 7 htiles x 8 = 56
// rows exactly -> no row masking. LDS holds ONLY the xs halo tile
// (CH x 14 rows x 64 cols, value col cc = w+4, blocks 1..14 valid), XOR
// swizzle storage_blk = value_blk ^ (row&7) applied BOTH at stage (pre-
// swizzled global source, linear LDS dest) and at ds_read. x1 comes from
// global (identical lines across the 7 dy-waves -> L1), weights from SGPRs.
// LDS padded to 55 KB: caps at 2 blocks/CU so the allocator targets
// 4 waves/SIMD (128-VGPR budget) instead of squeezing to 64 (r9 mechanism).
__global__ __launch_bounds__(448, 2)
void wcorr(const float* __restrict__ x, const float* __restrict__ wgt,
           float* __restrict__ out) {
  __shared__ float lds[LDS_F];
  __shared__ float lds_pad[PAD_F];
  asm volatile("" :: "v"(&lds_pad[threadIdx.x & 63]));  // keep pad allocated

  int bid = blockIdx.x;
  // bijective XCD swizzle: nwg = 3584 = 8*448; htile fastest so blocks
  // sharing halo rows / x[t] lines stay on one XCD's L2.
  int wid = (bid & 7) * 448 + (bid >> 3);
  int htile = wid % 7;
  int rest = wid / 7;              // (b*4 + g)*16 + t
  int t = rest & 15;
  int bg = rest >> 4;
  int g = bg & 3;
  int b = bg >> 2;
  int h0 = htile * 8;

  int tid = threadIdx.x;
  int lane = tid & 63;
  int dyu = __builtin_amdgcn_readfirstlane(tid >> 6);  // 0..6, wave-uniform
  int tx = lane & 7;
  int h = lane >> 3;               // 0..7
  bool wr = (tx < 7);
  int txc = wr ? tx : 6;           // tx==7 duplicates tx==6 (store-masked)
  int w0 = 8 * txc;
  int r = h + dyu;                 // xs local row 0..13 (global hh = h0-3+r)
  int t1 = (t > 0) ? (t - 1) : 0;

  for (int i = tid; i < LDS_F; i += 448) lds[i] = 0.0f;

  const size_t cstride = (size_t)L_ * HW_;
  const float* xg = x + ((size_t)b * C_ + (size_t)g * 32) * cstride;
  const float* x1b = xg + (size_t)t1 * HW_ + (size_t)(h0 + h) * W_ + w0;
  const float* wgb = wgt + (size_t)(g * 32) * (L_ * 49) + t * 49 + dyu * 7;

  // staging: task tau in [0,896) -> 16B at LDS byte fb*4 + tau*16.
  // rho = tau>>4: ci = rho/14, row rr = rho%14; sb = tau&15 = storage block;
  // slot sb receives value block vb = sb ^ (rr&7)  (pre-swizzled source).
  auto stage = [&](int tau, int k) {
    int fb = (k & 1) * XS_F;
    int c0 = k * CH_;
    int rho = tau >> 4;
    int sb = tau & 15;
    int ci = rho / 14;
    int rr = rho - ci * 14;
    int vb = sb ^ (rr & 7);
    int hh = h0 - 3 + rr;
    bool ok = (vb >= 1) && (vb <= 14) && (hh >= 0) && (hh < H_);
    const float* src = xg + (size_t)(c0 + ci) * cstride + (size_t)t * HW_
                          + hh * W_ + (vb * 4 - 4);
    float* dst = &lds[fb + (tau & ~63) * 4];   // wave-uniform base
    if (ok)
      __builtin_amdgcn_global_load_lds((glb_u32*)src, (lds_u32*)dst, 16, 0, 0);
  };

  float acc[7][8];
  #pragma unroll
  for (int i = 0; i < 7; ++i)
    #pragma unroll
    for (int p = 0; p < 8; ++p) acc[i][p] = 0.0f;

  __syncthreads();                 // zero-init visible before staging
  stage(tid, 0);
  stage(tid + 448, 0);
  __syncthreads();                 // drains vmcnt(0): chunk 0 ready

  #pragma unroll 2
  for (int k = 0; k < NCK_; ++k) {
    if (k + 1 < NCK_) {            // issue-early: flies during compute(k)
      stage(tid, k + 1);
      stage(tid + 448, k + 1);
    }
    int fb = (k & 1) * XS_F;
    int c0 = k * CH_;
    int s = r & 7;
    #pragma unroll
    for (int ci = 0; ci < CH_; ++ci) {
      const f4* xsrow = (const f4*)&lds[fb + (ci * 14 + r) * RS_];
      f4 q0 = xsrow[(2 * txc + 0) ^ s];
      f4 q1 = xsrow[(2 * txc + 1) ^ s];
      f4 q2 = xsrow[(2 * txc + 2) ^ s];
      f4 q3 = xsrow[(2 * txc + 3) ^ s];
      const float* x1p = x1b + (size_t)(c0 + ci) * cstride;   // global, L1-hot
      f4 a0 = *(const f4*)(x1p);
      f4 a1 = *(const f4*)(x1p + 4);
      const float* wp = wgb + (size_t)(c0 + ci) * (L_ * 49);  // uniform->s_load
      float w7[7];
      #pragma unroll
      for (int d = 0; d < 7; ++d) w7[d] = wp[d];
      // rr_[i] = value at cc = 8*txc + i; (p,dx) needs cc = w0+p+dx+1
      float rr_[16] = {q0.x, q0.y, q0.z, q0.w, q1.x, q1.y, q1.z, q1.w,
                       q2.x, q2.y, q2.z, q2.w, q3.x, q3.y, q3.z, q3.w};
      float x1v[8] = {a0.x, a0.y, a0.z, a0.w, a1.x, a1.y, a1.z, a1.w};
      #pragma unroll
      for (int dxx = 0; dxx < 7; ++dxx) {
        #pragma unroll
        for (int p = 0; p < 8; ++p) {
          acc[dxx][p] = fmaf(w7[dxx], x1v[p] * rr_[p + dxx + 1], acc[dxx][p]);
        }
      }
    }
    __syncthreads();   // compute(k) done; stage(k+1) drained at barrier
  }

  if (wr) {
    const float sc = 1.0f / 32.0f;
    #pragma unroll
    for (int dxx = 0; dxx < 7; ++dxx) {
      int och = (dyu * 7 + dxx) * G_ + g;
      float* op = out + (((size_t)b * 196 + och) * L_ + t) * (size_t)HW_
                      + (size_t)(h0 + h) * W_ + w0;
      f4 o0 = {acc[dxx][0] * sc, acc[dxx][1] * sc,
               acc[dxx][2] * sc, acc[dxx][3] * sc};
      f4 o1 = {acc[dxx][4] * sc, acc[dxx][5] * sc,
               acc[dxx][6] * sc, acc[dxx][7] * sc};
      __builtin_nontemporal_store(o0, (f4*)op);
      __builtin_nontemporal_store(o1, (f4*)(op + 4));
    }
  }
}

extern "C" void kernel_launch(void* const* d_in, const int* in_sizes, int n_in,
                              void* d_out, int out_size, void* d_ws, size_t ws_size,
                              hipStream_t stream) {
  const float* x = (const float*)d_in[0];
  const float* w = (const float*)d_in[1];
  float* o = (float*)d_out;
  dim3 grid(3584), block(448);
  hipLaunchKernelGGL(wcorr, grid, block, 0, stream, x, w, o);
}